// Round 9
// baseline (2868.540 us; speedup 1.0000x reference)
//
#include <hip/hip_runtime.h>

// Problem dims
#define BB 32
#define LL 1024
#define DD 512
#define HH 8
#define DHH 64
#define DFF 2048
#define NLAYERS 6
#define AA 21
#define MTOT (BB*LL)   // 32768 rows
#define QS 1536        // qkv row stride

typedef unsigned short u16;
typedef __bf16 bf16x8 __attribute__((ext_vector_type(8)));
typedef float f32x4 __attribute__((ext_vector_type(4)));
typedef u16 u16x8 __attribute__((ext_vector_type(8)));

__device__ __forceinline__ float bf2f(u16 u) {
    return __uint_as_float(((unsigned int)u) << 16);
}
__device__ __forceinline__ u16 f2bf(float f) {
    unsigned int i = __float_as_uint(f);
    unsigned int r = i + 0x7FFFu + ((i >> 16) & 1u);
    return (u16)(r >> 16);
}

// ------- dtype detect: sample even-index u16s of tok_emb -------
__global__ void detect_kernel(const void* __restrict__ tok, int* __restrict__ flag) {
    __shared__ int cnt[256];
    int t = threadIdx.x;
    const u16* p = (const u16*)tok;
    int c = 0;
    #pragma unroll
    for (int j = 0; j < 8; j++) {
        u16 u = p[2 * (t * 8 + j)];
        int e = (u >> 7) & 0xFF;
        c += (e >= 97 && e <= 137) ? 1 : 0;
    }
    cnt[t] = c;
    __syncthreads();
    for (int s = 128; s; s >>= 1) {
        if (t < s) cnt[t] += cnt[t + s];
        __syncthreads();
    }
    if (t == 0) flag[0] = (cnt[0] > 1024) ? 1 : 0;
}

// ------- batched small-tensor convert -------
#define NTAB 13
struct ConvTab {
    const void* src[NTAB];
    unsigned long long dstOff[NTAB];
    int n[NTAB];
    int chunk[NTAB];
    int lstride[NTAB];
};
__global__ __launch_bounds__(256) void conv_small(ConvTab tab, u16* __restrict__ spBase,
                                                  const int* __restrict__ flag, int total) {
    int i = blockIdx.x * 256 + threadIdx.x;
    if (i >= total) return;
    int fl = flag[0];
    #pragma unroll 1
    for (int e = 0; e < NTAB; e++) {
        if (i < tab.n[e]) {
            const void* s = tab.src[e];
            u16 val = fl ? ((const u16*)s)[i] : f2bf(((const float*)s)[i]);
            int c = i / tab.chunk[e];
            int r = i - c * tab.chunk[e];
            spBase[tab.dstOff[e] + (size_t)c * tab.lstride[e] + r] = val;
            return;
        }
        i -= tab.n[e];
    }
}

// ------- batched convert+transpose -------
__global__ __launch_bounds__(256) void conv_T(const void* __restrict__ src,
                                              u16* __restrict__ dst, int R, int C,
                                              const int* __restrict__ flag, int dstZS) {
    __shared__ u16 tile[32][33];
    int z = blockIdx.z;
    size_t zoffS = (size_t)z * R * C;
    size_t zoffD = (size_t)z * dstZS;
    int bx = blockIdx.x * 32, by = blockIdx.y * 32;
    int tx = threadIdx.x & 31, ty = threadIdx.x >> 5;
    int fl = flag[0];
    const u16* s16 = (const u16*)src + zoffS;
    const float* s32 = (const float*)src + zoffS;
    #pragma unroll
    for (int r = 0; r < 4; r++) {
        size_t idx = (size_t)(by + ty * 4 + r) * C + bx + tx;
        tile[ty * 4 + r][tx] = fl ? s16[idx] : f2bf(s32[idx]);
    }
    __syncthreads();
    #pragma unroll
    for (int r = 0; r < 4; r++)
        dst[zoffD + (size_t)(bx + ty * 4 + r) * R + by + tx] = tile[tx][ty * 4 + r];
}

// ------- wout pad -------
__global__ __launch_bounds__(256) void woutpad_kernel(const void* __restrict__ wout,
                                                      const void* __restrict__ bout,
                                                      u16* __restrict__ wpad,
                                                      u16* __restrict__ bpad,
                                                      const int* __restrict__ flag) {
    int i = blockIdx.x * 256 + threadIdx.x;
    int fl = flag[0];
    if (i < 128 * 512) {
        int n = i >> 9, kk = i & 511;
        u16 val = 0;
        if (n < AA) val = fl ? ((const u16*)wout)[kk * AA + n] : f2bf(((const float*)wout)[kk * AA + n]);
        wpad[(size_t)n * 512 + kk] = val;
    }
    if (i < 128) {
        u16 val = 0;
        if (i < AA) val = fl ? ((const u16*)bout)[i] : f2bf(((const float*)bout)[i]);
        bpad[i] = val;
    }
}

// ---------------- embed ----------------
__global__ __launch_bounds__(128) void embed_kernel(const int* __restrict__ x,
                                                    const u16* __restrict__ tok_emb,
                                                    const u16* __restrict__ pos_emb,
                                                    float* __restrict__ h) {
    int row = blockIdx.x;
    int l = row & (LL - 1);
    int tok = x[row];
    int c = threadIdx.x * 4;
    ushort4 te = *(const ushort4*)(tok_emb + (size_t)tok * DD + c);
    ushort4 pe = *(const ushort4*)(pos_emb + (size_t)l * DD + c);
    float4 o;
    o.x = bf2f(te.x) + bf2f(pe.x);
    o.y = bf2f(te.y) + bf2f(pe.y);
    o.z = bf2f(te.z) + bf2f(pe.z);
    o.w = bf2f(te.w) + bf2f(pe.w);
    *(float4*)(h + (size_t)row * DD + c) = o;
}

// ---------------- LayerNorm ----------------
__global__ __launch_bounds__(256) void ln_kernel(const float* __restrict__ h,
                                                 const u16* __restrict__ s,
                                                 const u16* __restrict__ b,
                                                 u16* __restrict__ outp) {
    int row = blockIdx.x * 4 + (threadIdx.x >> 6);
    int lane = threadIdx.x & 63;
    const float* hr = h + (size_t)row * DD + lane * 8;
    f32x4 v0 = *(const f32x4*)hr;
    f32x4 v1 = *(const f32x4*)(hr + 4);
    float sum = v0[0]+v0[1]+v0[2]+v0[3]+v1[0]+v1[1]+v1[2]+v1[3];
    #pragma unroll
    for (int off = 32; off; off >>= 1) sum += __shfl_xor(sum, off, 64);
    float mu = sum * (1.0f / DD);
    float var = 0.f;
    #pragma unroll
    for (int i = 0; i < 4; i++) {
        float d0 = v0[i] - mu, d1 = v1[i] - mu;
        var += d0 * d0 + d1 * d1;
    }
    #pragma unroll
    for (int off = 32; off; off >>= 1) var += __shfl_xor(var, off, 64);
    float rs = rsqrtf(var * (1.0f / DD) + 1e-6f);
    u16x8 sv = *(const u16x8*)(s + lane * 8);
    u16x8 bv = *(const u16x8*)(b + lane * 8);
    u16x8 o;
    #pragma unroll
    for (int i = 0; i < 8; i++) {
        float xv = (i < 4) ? v0[i] : v1[i - 4];
        o[i] = f2bf((xv - mu) * rs * bf2f(sv[i]) + bf2f(bv[i]));
    }
    *(u16x8*)(outp + (size_t)row * DD + lane * 8) = o;
}

// ---------------- GEMM: C = A(MxK, lda) @ BT(NxK)^T + bias ----------------
// r7: XOR bank swizzle (conflicts -> 0). r8: XCD-aware block swizzle (FETCH -> unique bytes).
// r9: BK=64 — 8 GLD16 + 32 MFMA per barrier-pair (vs 4+16) to halve barrier-drain per FLOP.
// LDS row = 128 B (all 32 banks); slot swizzle: global chunk fetched = (tid&7)^((tid>>3)&7),
// read slot = (s*4 + (lane>>4)) ^ (lm&7) -> <=2 lanes per 4-bank group per phase (free).
// EPI 0: bf16 ; EPI 1: bf16 gelu ; EPI 2: Cf += ; EPI 3: cols<21 dtype per flag ;
// EPI 4: bf16 out = x + bias + Cf
#define GLD16(gp, lp) __builtin_amdgcn_global_load_lds( \
    (const __attribute__((address_space(1))) void*)(gp), \
    (__attribute__((address_space(3))) void*)(lp), 16, 0, 0)

template <int EPI>
__global__ __launch_bounds__(256) void gemm_bt(const u16* __restrict__ A,
                                               const u16* __restrict__ BT,
                                               const u16* __restrict__ bias,
                                               u16* __restrict__ Cb,
                                               float* __restrict__ Cf,
                                               int M, int N, int K, int lda,
                                               const int* __restrict__ flag) {
    __shared__ __align__(16) u16 Als[128 * 64];
    __shared__ __align__(16) u16 Bls[128 * 64];
    const int tid  = threadIdx.x;
    const int lane = tid & 63;
    const int wave = tid >> 6;

    // XCD-aware remap (xcd = linear bid % 8 on MI355X)
    int gx = gridDim.x, gy = gridDim.y;
    int tileX, tileY;
    if ((gy & 7) == 0) {
        int bid = blockIdx.y * gx + blockIdx.x;
        int xcd = bid & 7;
        int idx = bid >> 3;
        int stripe = gy >> 3;              // M-tiles per XCD
        tileX = idx % gx;                  // N fastest within XCD
        tileY = xcd * stripe + idx / gx;
    } else {
        tileX = blockIdx.x; tileY = blockIdx.y;
    }
    const int tileM = tileY * 128;
    const int tileN = tileX * 128;
    const int wm = (wave & 1) * 64;
    const int wn = (wave >> 1) * 64;

    // staging: row = q*32 + (tid>>3), fetched chunk = (tid&7) ^ (row&7)
    const int r8 = tid >> 3;                              // 0..31
    const int c8 = ((tid & 7) ^ (r8 & 7)) * 8;

    const u16* Ag = A  + (size_t)(tileM + r8) * lda + c8;
    const u16* Bg = BT + (size_t)(tileN + r8) * K + c8;

    f32x4 acc[4][4] = {};
    const int lm = lane & 15;
    const int g  = lane >> 4;
    const int slot0 = ((g)     ^ (lm & 7)) * 8;          // kstep 0 read slot
    const int slot1 = ((4 + g) ^ (lm & 7)) * 8;          // kstep 1 read slot

    for (int k0 = 0; k0 < K; k0 += 64) {
        #pragma unroll
        for (int q = 0; q < 4; q++) {
            GLD16(Ag + (size_t)q * 32 * lda + k0, Als + q * 2048 + tid * 8);
            GLD16(Bg + (size_t)q * 32 * K   + k0, Bls + q * 2048 + tid * 8);
        }
        __syncthreads();
        #pragma unroll
        for (int s = 0; s < 2; s++) {
            const int sl = s ? slot1 : slot0;
            bf16x8 af[4], bfr[4];
            #pragma unroll
            for (int i = 0; i < 4; i++)
                af[i] = *(const bf16x8*)(Als + (wm + i * 16 + lm) * 64 + sl);
            #pragma unroll
            for (int j = 0; j < 4; j++)
                bfr[j] = *(const bf16x8*)(Bls + (wn + j * 16 + lm) * 64 + sl);
            #pragma unroll
            for (int i = 0; i < 4; i++)
                #pragma unroll
                for (int j = 0; j < 4; j++)
                    acc[i][j] = __builtin_amdgcn_mfma_f32_16x16x32_bf16(af[i], bfr[j], acc[i][j], 0, 0, 0);
        }
        __syncthreads();
    }

    int fl = 0;
    if constexpr (EPI == 3) fl = flag[0];
    const int r0 = (lane >> 4) * 4;     // C/D: col=lane&15, row=(lane>>4)*4+reg
    #pragma unroll
    for (int j = 0; j < 4; j++) {
        int col = tileN + wn + j * 16 + lm;
        float bv = bf2f(bias[col]);
        #pragma unroll
        for (int i = 0; i < 4; i++) {
            int row = tileM + wm + i * 16 + r0;
            #pragma unroll
            for (int r = 0; r < 4; r++) {
                float xv = acc[i][j][r] + bv;
                if constexpr (EPI == 0) {
                    Cb[(size_t)(row + r) * N + col] = f2bf(xv);
                } else if constexpr (EPI == 1) {
                    float u = 1.5957691216057308f * (xv + 0.044715f * xv * xv * xv);
                    float t = 1.0f - 2.0f / (__expf(u) + 1.0f);
                    Cb[(size_t)(row + r) * N + col] = f2bf(0.5f * xv * (1.0f + t));
                } else if constexpr (EPI == 2) {
                    Cf[(size_t)(row + r) * N + col] += xv;
                } else if constexpr (EPI == 4) {
                    size_t idx = (size_t)(row + r) * N + col;
                    Cb[idx] = f2bf(xv + Cf[idx]);
                } else {
                    if (col < AA) {
                        size_t idx = (size_t)(row + r) * AA + col;
                        if (fl) Cb[idx] = f2bf(xv);
                        else    Cf[idx] = xv;
                    }
                }
            }
        }
    }
}

// ---------------- sparse attention v3: one wave per (b,l), all heads; lane = h*8 + d8 ----------------
__global__ __launch_bounds__(256) void attn_kernel(u16* qkv) {
    int bl   = blockIdx.x * 4 + (threadIdx.x >> 6);   // b*L + l
    int lane = threadIdx.x & 63;
    int l    = bl & (LL - 1);
    int lo   = (l & ~3) - 4; if (lo < 0) lo = 0;
    int nj   = l - lo + 1;                             // 1..8 valid keys

    size_t qrow = (size_t)bl * QS;
    int off = lane * 8;

    u16x8 q8 = *(const u16x8*)(qkv + qrow + off);
    float qf[8];
    #pragma unroll
    for (int i = 0; i < 8; i++) qf[i] = bf2f(q8[i]) * 0.125f;

    size_t base = (size_t)(bl - (l - lo)) * QS;        // row lo
    float sc[8];
    u16x8 v8[8];
    #pragma unroll
    for (int j = 0; j < 8; j++) {
        int jc = (j < nj) ? j : (nj - 1);
        const u16* krow = qkv + base + (size_t)jc * QS;
        u16x8 k8 = *(const u16x8*)(krow + 512 + off);
        v8[j]    = *(const u16x8*)(krow + 1024 + off);
        float t = 0.f;
        #pragma unroll
        for (int i = 0; i < 8; i++) t = fmaf(qf[i], bf2f(k8[i]), t);
        t += __shfl_xor(t, 1, 64);
        t += __shfl_xor(t, 2, 64);
        t += __shfl_xor(t, 4, 64);
        sc[j] = (j < nj) ? t : -1e30f;
    }
    float m = sc[0];
    #pragma unroll
    for (int j = 1; j < 8; j++) m = fmaxf(m, sc[j]);
    float p[8], den = 0.f;
    #pragma unroll
    for (int j = 0; j < 8; j++) { p[j] = __expf(sc[j] - m); den += p[j]; }
    float inv = 1.0f / den;
    float o[8] = {};
    #pragma unroll
    for (int j = 0; j < 8; j++)
        #pragma unroll
        for (int i = 0; i < 8; i++) o[i] = fmaf(p[j], bf2f(v8[j][i]), o[i]);
    u16x8 ov;
    #pragma unroll
    for (int i = 0; i < 8; i++) ov[i] = f2bf(o[i] * inv);
    *(u16x8*)(qkv + qrow + off) = ov;
}

extern "C" void kernel_launch(void* const* d_in, const int* in_sizes, int n_in,
                              void* d_out, int out_size, void* d_ws, size_t ws_size,
                              hipStream_t stream) {
    const int base = n_in - 22;
    const int*  x    = (const int*)d_in[0];
    const void* tokI = d_in[2 + base];
    const void* posI = d_in[3 + base];
    const void* wqI  = d_in[4 + base];
    const void* bqI  = d_in[5 + base];
    const void* wkI  = d_in[6 + base];
    const void* bkI  = d_in[7 + base];
    const void* wvI  = d_in[8 + base];
    const void* bvI  = d_in[9 + base];
    const void* woI  = d_in[10 + base];
    const void* boI  = d_in[11 + base];
    const void* ln1sI = d_in[12 + base];
    const void* ln1bI = d_in[13 + base];
    const void* ln2sI = d_in[14 + base];
    const void* ln2bI = d_in[15 + base];
    const void* w1I  = d_in[16 + base];
    const void* b1I  = d_in[17 + base];
    const void* w2I  = d_in[18 + base];
    const void* b2I  = d_in[19 + base];
    const void* woutI = d_in[20 + base];
    const void* boutI = d_in[21 + base];

    char* ws = (char*)d_ws;
    float* h   = (float*)(ws + 0);                 // 64 MB fp32 residual
    u16*  hn   = (u16*)(ws + 67108864);            // 32 MB
    u16*  qkv  = (u16*)(ws + 100663296);           // 96 MB packed qkv (stride 1536); mid reuses
    u16*  wT   = (u16*)(ws + 201326592);           // 36 MB transposed weights
    u16*  sp   = (u16*)(ws + 239075328);           // small params
    int* flag  = (int*)(ws + 240500736);

    u16* mid = qkv;                                // 16384x2048 bf16 = 64 MB

    u16* wqkvT = wT;                               // 6 x (1536x512)
    u16* woT   = wT + 4718592;                     // 6 x (512x512)
    u16* w1T   = wT + 6291456;                     // 6 x (2048x512)
    u16* w2T   = wT + 12582912;                    // 6 x (512x2048)

    const unsigned long long oWoutPad = 0;
    const unsigned long long oBoutPad = 65536;
    const unsigned long long oTok     = 65664;
    const unsigned long long oPos     = 76416;
    const unsigned long long oQkvB    = 600704;
    const unsigned long long oBo      = 609920;
    const unsigned long long oB1      = 612992;
    const unsigned long long oB2      = 625280;
    const unsigned long long oLn1s    = 628352;
    const unsigned long long oLn1b    = 631424;
    const unsigned long long oLn2s    = 634496;
    const unsigned long long oLn2b    = 637568;

    detect_kernel<<<1, 256, 0, stream>>>(tokI, flag);

    ConvTab tab;
    const void* srcs[NTAB] = {tokI, bqI, bkI, bvI, boI, b1I, b2I, ln1sI, ln1bI, ln2sI, ln2bI, posI, tokI};
    unsigned long long offs[NTAB] = {oTok, oQkvB, oQkvB + 512, oQkvB + 1024, oBo, oB1, oB2,
                                     oLn1s, oLn1b, oLn2s, oLn2b, oPos, oTok};
    int ns[NTAB]     = {10752, 3072, 3072, 3072, 3072, 12288, 3072, 3072, 3072, 3072, 3072, 524288, 0};
    int chunks[NTAB] = {10752, 512, 512, 512, 3072, 12288, 3072, 3072, 3072, 3072, 3072, 524288, 1};
    int lstr[NTAB]   = {10752, 1536, 1536, 1536, 3072, 12288, 3072, 3072, 3072, 3072, 3072, 524288, 1};
    int total = 0;
    for (int e = 0; e < NTAB; e++) {
        tab.src[e] = srcs[e]; tab.dstOff[e] = offs[e]; tab.n[e] = ns[e];
        tab.chunk[e] = chunks[e]; tab.lstride[e] = lstr[e];
        total += ns[e];
    }
    conv_small<<<(total + 255) / 256, 256, 0, stream>>>(tab, sp, flag, total);
    woutpad_kernel<<<256, 256, 0, stream>>>(woutI, boutI, sp + oWoutPad, sp + oBoutPad, flag);

    conv_T<<<dim3(16, 16, 6), 256, 0, stream>>>(wqI, wqkvT,          DD, DD, flag, 786432);
    conv_T<<<dim3(16, 16, 6), 256, 0, stream>>>(wkI, wqkvT + 262144, DD, DD, flag, 786432);
    conv_T<<<dim3(16, 16, 6), 256, 0, stream>>>(wvI, wqkvT + 524288, DD, DD, flag, 786432);
    conv_T<<<dim3(16, 16, 6), 256, 0, stream>>>(woI, woT, DD, DD, flag, 262144);
    conv_T<<<dim3(64, 16, 6), 256, 0, stream>>>(w1I, w1T, DD, DFF, flag, 1048576);
    conv_T<<<dim3(16, 64, 6), 256, 0, stream>>>(w2I, w2T, DFF, DD, flag, 1048576);

    embed_kernel<<<MTOT, 128, 0, stream>>>(x, sp + oTok, sp + oPos, h);

    for (int l = 0; l < NLAYERS; l++) {
        u16* wqkvTl = wqkvT + (size_t)l * 786432;
        u16* woTl   = woT + (size_t)l * 262144;
        u16* w1Tl   = w1T + (size_t)l * 1048576;
        u16* w2Tl   = w2T + (size_t)l * 1048576;

        ln_kernel<<<MTOT / 4, 256, 0, stream>>>(h, sp + oLn1s + l * DD, sp + oLn1b + l * DD, hn);

        gemm_bt<0><<<dim3(QS / 128, MTOT / 128), 256, 0, stream>>>(
            hn, wqkvTl, sp + oQkvB + l * QS, qkv, nullptr, MTOT, QS, DD, DD, flag);

        attn_kernel<<<MTOT / 4, 256, 0, stream>>>(qkv);

        gemm_bt<2><<<dim3(DD / 128, MTOT / 128), 256, 0, stream>>>(
            qkv, woTl, sp + oBo + l * DD, nullptr, h, MTOT, DD, DD, QS, flag);

        ln_kernel<<<MTOT / 4, 256, 0, stream>>>(h, sp + oLn2s + l * DD, sp + oLn2b + l * DD, hn);

        for (int half = 0; half < 2; half++) {
            const u16* Ahn = hn + (size_t)half * 16384 * DD;
            float* hHalf = h + (size_t)half * 16384 * DD;
            gemm_bt<1><<<dim3(DFF / 128, 16384 / 128), 256, 0, stream>>>(
                Ahn, w1Tl, sp + oB1 + l * DFF, mid, nullptr, 16384, DFF, DD, DD, flag);
            if (l < NLAYERS - 1) {
                gemm_bt<2><<<dim3(DD / 128, 16384 / 128), 256, 0, stream>>>(
                    mid, w2Tl, sp + oB2 + l * DD, nullptr, hHalf, 16384, DD, DFF, DFF, flag);
            } else {
                gemm_bt<4><<<dim3(DD / 128, 16384 / 128), 256, 0, stream>>>(
                    mid, w2Tl, sp + oB2 + l * DD, hn + (size_t)half * 16384 * DD, hHalf,
                    16384, DD, DFF, DFF, flag);
            }
        }
    }

    gemm_bt<3><<<dim3(1, MTOT / 128), 256, 0, stream>>>(
        hn, sp + oWoutPad, sp + oBoutPad, (u16*)d_out, (float*)d_out, MTOT, 128, DD, DD, flag);
}

// Round 10
// 2738.780 us; speedup vs baseline: 1.0474x; 1.0474x over previous
//
#include <hip/hip_runtime.h>

// Problem dims
#define BB 32
#define LL 1024
#define DD 512
#define HH 8
#define DHH 64
#define DFF 2048
#define NLAYERS 6
#define AA 21
#define MTOT (BB*LL)   // 32768 rows
#define QS 1536        // qkv row stride

typedef unsigned short u16;
typedef __bf16 bf16x8 __attribute__((ext_vector_type(8)));
typedef float f32x4 __attribute__((ext_vector_type(4)));
typedef u16 u16x8 __attribute__((ext_vector_type(8)));

__device__ __forceinline__ float bf2f(u16 u) {
    return __uint_as_float(((unsigned int)u) << 16);
}
__device__ __forceinline__ u16 f2bf(float f) {
    unsigned int i = __float_as_uint(f);
    unsigned int r = i + 0x7FFFu + ((i >> 16) & 1u);
    return (u16)(r >> 16);
}

// ------- dtype detect: sample even-index u16s of tok_emb -------
__global__ void detect_kernel(const void* __restrict__ tok, int* __restrict__ flag) {
    __shared__ int cnt[256];
    int t = threadIdx.x;
    const u16* p = (const u16*)tok;
    int c = 0;
    #pragma unroll
    for (int j = 0; j < 8; j++) {
        u16 u = p[2 * (t * 8 + j)];
        int e = (u >> 7) & 0xFF;
        c += (e >= 97 && e <= 137) ? 1 : 0;
    }
    cnt[t] = c;
    __syncthreads();
    for (int s = 128; s; s >>= 1) {
        if (t < s) cnt[t] += cnt[t + s];
        __syncthreads();
    }
    if (t == 0) flag[0] = (cnt[0] > 1024) ? 1 : 0;
}

// ------- batched small-tensor convert -------
#define NTAB 13
struct ConvTab {
    const void* src[NTAB];
    unsigned long long dstOff[NTAB];
    int n[NTAB];
    int chunk[NTAB];
    int lstride[NTAB];
};
__global__ __launch_bounds__(256) void conv_small(ConvTab tab, u16* __restrict__ spBase,
                                                  const int* __restrict__ flag, int total) {
    int i = blockIdx.x * 256 + threadIdx.x;
    if (i >= total) return;
    int fl = flag[0];
    #pragma unroll 1
    for (int e = 0; e < NTAB; e++) {
        if (i < tab.n[e]) {
            const void* s = tab.src[e];
            u16 val = fl ? ((const u16*)s)[i] : f2bf(((const float*)s)[i]);
            int c = i / tab.chunk[e];
            int r = i - c * tab.chunk[e];
            spBase[tab.dstOff[e] + (size_t)c * tab.lstride[e] + r] = val;
            return;
        }
        i -= tab.n[e];
    }
}

// ------- batched convert+transpose -------
__global__ __launch_bounds__(256) void conv_T(const void* __restrict__ src,
                                              u16* __restrict__ dst, int R, int C,
                                              const int* __restrict__ flag, int dstZS) {
    __shared__ u16 tile[32][33];
    int z = blockIdx.z;
    size_t zoffS = (size_t)z * R * C;
    size_t zoffD = (size_t)z * dstZS;
    int bx = blockIdx.x * 32, by = blockIdx.y * 32;
    int tx = threadIdx.x & 31, ty = threadIdx.x >> 5;
    int fl = flag[0];
    const u16* s16 = (const u16*)src + zoffS;
    const float* s32 = (const float*)src + zoffS;
    #pragma unroll
    for (int r = 0; r < 4; r++) {
        size_t idx = (size_t)(by + ty * 4 + r) * C + bx + tx;
        tile[ty * 4 + r][tx] = fl ? s16[idx] : f2bf(s32[idx]);
    }
    __syncthreads();
    #pragma unroll
    for (int r = 0; r < 4; r++)
        dst[zoffD + (size_t)(bx + ty * 4 + r) * R + by + tx] = tile[tx][ty * 4 + r];
}

// ------- wout pad -------
__global__ __launch_bounds__(256) void woutpad_kernel(const void* __restrict__ wout,
                                                      const void* __restrict__ bout,
                                                      u16* __restrict__ wpad,
                                                      u16* __restrict__ bpad,
                                                      const int* __restrict__ flag) {
    int i = blockIdx.x * 256 + threadIdx.x;
    int fl = flag[0];
    if (i < 128 * 512) {
        int n = i >> 9, kk = i & 511;
        u16 val = 0;
        if (n < AA) val = fl ? ((const u16*)wout)[kk * AA + n] : f2bf(((const float*)wout)[kk * AA + n]);
        wpad[(size_t)n * 512 + kk] = val;
    }
    if (i < 128) {
        u16 val = 0;
        if (i < AA) val = fl ? ((const u16*)bout)[i] : f2bf(((const float*)bout)[i]);
        bpad[i] = val;
    }
}

// ---------------- embed ----------------
__global__ __launch_bounds__(128) void embed_kernel(const int* __restrict__ x,
                                                    const u16* __restrict__ tok_emb,
                                                    const u16* __restrict__ pos_emb,
                                                    float* __restrict__ h) {
    int row = blockIdx.x;
    int l = row & (LL - 1);
    int tok = x[row];
    int c = threadIdx.x * 4;
    ushort4 te = *(const ushort4*)(tok_emb + (size_t)tok * DD + c);
    ushort4 pe = *(const ushort4*)(pos_emb + (size_t)l * DD + c);
    float4 o;
    o.x = bf2f(te.x) + bf2f(pe.x);
    o.y = bf2f(te.y) + bf2f(pe.y);
    o.z = bf2f(te.z) + bf2f(pe.z);
    o.w = bf2f(te.w) + bf2f(pe.w);
    *(float4*)(h + (size_t)row * DD + c) = o;
}

// ---------------- LayerNorm ----------------
__global__ __launch_bounds__(256) void ln_kernel(const float* __restrict__ h,
                                                 const u16* __restrict__ s,
                                                 const u16* __restrict__ b,
                                                 u16* __restrict__ outp) {
    int row = blockIdx.x * 4 + (threadIdx.x >> 6);
    int lane = threadIdx.x & 63;
    const float* hr = h + (size_t)row * DD + lane * 8;
    f32x4 v0 = *(const f32x4*)hr;
    f32x4 v1 = *(const f32x4*)(hr + 4);
    float sum = v0[0]+v0[1]+v0[2]+v0[3]+v1[0]+v1[1]+v1[2]+v1[3];
    #pragma unroll
    for (int off = 32; off; off >>= 1) sum += __shfl_xor(sum, off, 64);
    float mu = sum * (1.0f / DD);
    float var = 0.f;
    #pragma unroll
    for (int i = 0; i < 4; i++) {
        float d0 = v0[i] - mu, d1 = v1[i] - mu;
        var += d0 * d0 + d1 * d1;
    }
    #pragma unroll
    for (int off = 32; off; off >>= 1) var += __shfl_xor(var, off, 64);
    float rs = rsqrtf(var * (1.0f / DD) + 1e-6f);
    u16x8 sv = *(const u16x8*)(s + lane * 8);
    u16x8 bv = *(const u16x8*)(b + lane * 8);
    u16x8 o;
    #pragma unroll
    for (int i = 0; i < 8; i++) {
        float xv = (i < 4) ? v0[i] : v1[i - 4];
        o[i] = f2bf((xv - mu) * rs * bf2f(sv[i]) + bf2f(bv[i]));
    }
    *(u16x8*)(outp + (size_t)row * DD + lane * 8) = o;
}

// ---------------- GEMM: C = A(MxK, lda) @ BT(NxK)^T + bias ----------------
// r7: XOR bank swizzle (conflicts -> 0). r8: XCD-aware block swizzle (FETCH -> unique).
// r10: double-buffered K-loop, ONE barrier/iter: GLD tile k+1 issued BEFORE the barrier so
// the mandatory vmcnt(0)-at-barrier drains a prefetch that overlapped the whole MFMA block,
// instead of stalling compute (intra-wave load/compute overlap the 2-barrier m97 shape lacks).
// EPI 0: bf16 ; EPI 1: bf16 gelu ; EPI 2: Cf += ; EPI 3: cols<21 dtype per flag ;
// EPI 4: bf16 out = x + bias + Cf
#define GLD16(gp, lp) __builtin_amdgcn_global_load_lds( \
    (const __attribute__((address_space(1))) void*)(gp), \
    (__attribute__((address_space(3))) void*)(lp), 16, 0, 0)

template <int EPI>
__global__ __launch_bounds__(256) void gemm_bt(const u16* __restrict__ A,
                                               const u16* __restrict__ BT,
                                               const u16* __restrict__ bias,
                                               u16* __restrict__ Cb,
                                               float* __restrict__ Cf,
                                               int M, int N, int K, int lda,
                                               const int* __restrict__ flag) {
    __shared__ __align__(16) u16 Als[2][128 * 32];
    __shared__ __align__(16) u16 Bls[2][128 * 32];
    const int tid  = threadIdx.x;
    const int lane = tid & 63;
    const int wave = tid >> 6;

    // XCD-aware remap (xcd = linear bid % 8 on MI355X)
    int gx = gridDim.x, gy = gridDim.y;
    int tileX, tileY;
    if ((gy & 7) == 0) {
        int bid = blockIdx.y * gx + blockIdx.x;
        int xcd = bid & 7;
        int idx = bid >> 3;
        int stripe = gy >> 3;              // M-tiles per XCD
        tileX = idx % gx;                  // N fastest within XCD
        tileY = xcd * stripe + idx / gx;
    } else {
        tileX = blockIdx.x; tileY = blockIdx.y;
    }
    const int tileM = tileY * 128;
    const int tileN = tileX * 128;
    const int wm = (wave & 1) * 64;
    const int wn = (wave >> 1) * 64;

    const int srow = tid >> 2;
    const int scol = (((tid & 3) ^ ((tid >> 3) & 3))) * 8;   // swizzled k-chunk this lane fetches

    const u16* Ag0 = A  + (size_t)(tileM + srow) * lda + scol;
    const u16* Ag1 = A  + (size_t)(tileM + 64 + srow) * lda + scol;
    const u16* Bg0 = BT + (size_t)(tileN + srow) * K + scol;
    const u16* Bg1 = BT + (size_t)(tileN + 64 + srow) * K + scol;

    f32x4 acc[4][4] = {};
    const int lm = lane & 15;
    const int lk = (((lane >> 4) ^ ((lm >> 1) & 3))) * 8;    // swizzled read slot (lane-constant)

    const int nk = K >> 5;
    // prologue: stage tile 0 into buffer 0
    GLD16(Ag0, Als[0] + tid * 8);
    GLD16(Ag1, Als[0] + 2048 + tid * 8);
    GLD16(Bg0, Bls[0] + tid * 8);
    GLD16(Bg1, Bls[0] + 2048 + tid * 8);
    __syncthreads();

    for (int kt = 0; kt < nk; kt++) {
        const int cur = kt & 1;
        const int nxt = cur ^ 1;
        if (kt + 1 < nk) {
            const int k1 = (kt + 1) << 5;
            GLD16(Ag0 + k1, Als[nxt] + tid * 8);
            GLD16(Ag1 + k1, Als[nxt] + 2048 + tid * 8);
            GLD16(Bg0 + k1, Bls[nxt] + tid * 8);
            GLD16(Bg1 + k1, Bls[nxt] + 2048 + tid * 8);
        }
        bf16x8 af[4], bfr[4];
        #pragma unroll
        for (int i = 0; i < 4; i++)
            af[i] = *(const bf16x8*)(Als[cur] + (wm + i * 16 + lm) * 32 + lk);
        #pragma unroll
        for (int j = 0; j < 4; j++)
            bfr[j] = *(const bf16x8*)(Bls[cur] + (wn + j * 16 + lm) * 32 + lk);
        #pragma unroll
        for (int i = 0; i < 4; i++)
            #pragma unroll
            for (int j = 0; j < 4; j++)
                acc[i][j] = __builtin_amdgcn_mfma_f32_16x16x32_bf16(af[i], bfr[j], acc[i][j], 0, 0, 0);
        __syncthreads();   // publishes buf[nxt] (vm drain) + protects buf[cur] (lgkm drain)
    }

    int fl = 0;
    if constexpr (EPI == 3) fl = flag[0];
    const int r0 = (lane >> 4) * 4;     // C/D: col=lane&15, row=(lane>>4)*4+reg
    #pragma unroll
    for (int j = 0; j < 4; j++) {
        int col = tileN + wn + j * 16 + lm;
        float bv = bf2f(bias[col]);
        #pragma unroll
        for (int i = 0; i < 4; i++) {
            int row = tileM + wm + i * 16 + r0;
            #pragma unroll
            for (int r = 0; r < 4; r++) {
                float xv = acc[i][j][r] + bv;
                if constexpr (EPI == 0) {
                    Cb[(size_t)(row + r) * N + col] = f2bf(xv);
                } else if constexpr (EPI == 1) {
                    float u = 1.5957691216057308f * (xv + 0.044715f * xv * xv * xv);
                    float t = 1.0f - 2.0f / (__expf(u) + 1.0f);
                    Cb[(size_t)(row + r) * N + col] = f2bf(0.5f * xv * (1.0f + t));
                } else if constexpr (EPI == 2) {
                    Cf[(size_t)(row + r) * N + col] += xv;
                } else if constexpr (EPI == 4) {
                    size_t idx = (size_t)(row + r) * N + col;
                    Cb[idx] = f2bf(xv + Cf[idx]);
                } else {
                    if (col < AA) {
                        size_t idx = (size_t)(row + r) * AA + col;
                        if (fl) Cb[idx] = f2bf(xv);
                        else    Cf[idx] = xv;
                    }
                }
            }
        }
    }
}

// ---------------- sparse attention v3: one wave per (b,l), all heads; lane = h*8 + d8 ----------------
__global__ __launch_bounds__(256) void attn_kernel(u16* qkv) {
    int bl   = blockIdx.x * 4 + (threadIdx.x >> 6);   // b*L + l
    int lane = threadIdx.x & 63;
    int l    = bl & (LL - 1);
    int lo   = (l & ~3) - 4; if (lo < 0) lo = 0;
    int nj   = l - lo + 1;                             // 1..8 valid keys

    size_t qrow = (size_t)bl * QS;
    int off = lane * 8;

    u16x8 q8 = *(const u16x8*)(qkv + qrow + off);
    float qf[8];
    #pragma unroll
    for (int i = 0; i < 8; i++) qf[i] = bf2f(q8[i]) * 0.125f;

    size_t base = (size_t)(bl - (l - lo)) * QS;        // row lo
    float sc[8];
    u16x8 v8[8];
    #pragma unroll
    for (int j = 0; j < 8; j++) {
        int jc = (j < nj) ? j : (nj - 1);
        const u16* krow = qkv + base + (size_t)jc * QS;
        u16x8 k8 = *(const u16x8*)(krow + 512 + off);
        v8[j]    = *(const u16x8*)(krow + 1024 + off);
        float t = 0.f;
        #pragma unroll
        for (int i = 0; i < 8; i++) t = fmaf(qf[i], bf2f(k8[i]), t);
        t += __shfl_xor(t, 1, 64);
        t += __shfl_xor(t, 2, 64);
        t += __shfl_xor(t, 4, 64);
        sc[j] = (j < nj) ? t : -1e30f;
    }
    float m = sc[0];
    #pragma unroll
    for (int j = 1; j < 8; j++) m = fmaxf(m, sc[j]);
    float p[8], den = 0.f;
    #pragma unroll
    for (int j = 0; j < 8; j++) { p[j] = __expf(sc[j] - m); den += p[j]; }
    float inv = 1.0f / den;
    float o[8] = {};
    #pragma unroll
    for (int j = 0; j < 8; j++)
        #pragma unroll
        for (int i = 0; i < 8; i++) o[i] = fmaf(p[j], bf2f(v8[j][i]), o[i]);
    u16x8 ov;
    #pragma unroll
    for (int i = 0; i < 8; i++) ov[i] = f2bf(o[i] * inv);
    *(u16x8*)(qkv + qrow + off) = ov;
}

extern "C" void kernel_launch(void* const* d_in, const int* in_sizes, int n_in,
                              void* d_out, int out_size, void* d_ws, size_t ws_size,
                              hipStream_t stream) {
    const int base = n_in - 22;
    const int*  x    = (const int*)d_in[0];
    const void* tokI = d_in[2 + base];
    const void* posI = d_in[3 + base];
    const void* wqI  = d_in[4 + base];
    const void* bqI  = d_in[5 + base];
    const void* wkI  = d_in[6 + base];
    const void* bkI  = d_in[7 + base];
    const void* wvI  = d_in[8 + base];
    const void* bvI  = d_in[9 + base];
    const void* woI  = d_in[10 + base];
    const void* boI  = d_in[11 + base];
    const void* ln1sI = d_in[12 + base];
    const void* ln1bI = d_in[13 + base];
    const void* ln2sI = d_in[14 + base];
    const void* ln2bI = d_in[15 + base];
    const void* w1I  = d_in[16 + base];
    const void* b1I  = d_in[17 + base];
    const void* w2I  = d_in[18 + base];
    const void* b2I  = d_in[19 + base];
    const void* woutI = d_in[20 + base];
    const void* boutI = d_in[21 + base];

    char* ws = (char*)d_ws;
    float* h   = (float*)(ws + 0);                 // 64 MB fp32 residual
    u16*  hn   = (u16*)(ws + 67108864);            // 32 MB
    u16*  qkv  = (u16*)(ws + 100663296);           // 96 MB packed qkv (stride 1536); mid reuses
    u16*  wT   = (u16*)(ws + 201326592);           // 36 MB transposed weights
    u16*  sp   = (u16*)(ws + 239075328);           // small params
    int* flag  = (int*)(ws + 240500736);

    u16* mid = qkv;                                // 16384x2048 bf16 = 64 MB

    u16* wqkvT = wT;                               // 6 x (1536x512)
    u16* woT   = wT + 4718592;                     // 6 x (512x512)
    u16* w1T   = wT + 6291456;                     // 6 x (2048x512)
    u16* w2T   = wT + 12582912;                    // 6 x (512x2048)

    const unsigned long long oWoutPad = 0;
    const unsigned long long oBoutPad = 65536;
    const unsigned long long oTok     = 65664;
    const unsigned long long oPos     = 76416;
    const unsigned long long oQkvB    = 600704;
    const unsigned long long oBo      = 609920;
    const unsigned long long oB1      = 612992;
    const unsigned long long oB2      = 625280;
    const unsigned long long oLn1s    = 628352;
    const unsigned long long oLn1b    = 631424;
    const unsigned long long oLn2s    = 634496;
    const unsigned long long oLn2b    = 637568;

    detect_kernel<<<1, 256, 0, stream>>>(tokI, flag);

    ConvTab tab;
    const void* srcs[NTAB] = {tokI, bqI, bkI, bvI, boI, b1I, b2I, ln1sI, ln1bI, ln2sI, ln2bI, posI, tokI};
    unsigned long long offs[NTAB] = {oTok, oQkvB, oQkvB + 512, oQkvB + 1024, oBo, oB1, oB2,
                                     oLn1s, oLn1b, oLn2s, oLn2b, oPos, oTok};
    int ns[NTAB]     = {10752, 3072, 3072, 3072, 3072, 12288, 3072, 3072, 3072, 3072, 3072, 524288, 0};
    int chunks[NTAB] = {10752, 512, 512, 512, 3072, 12288, 3072, 3072, 3072, 3072, 3072, 524288, 1};
    int lstr[NTAB]   = {10752, 1536, 1536, 1536, 3072, 12288, 3072, 3072, 3072, 3072, 3072, 524288, 1};
    int total = 0;
    for (int e = 0; e < NTAB; e++) {
        tab.src[e] = srcs[e]; tab.dstOff[e] = offs[e]; tab.n[e] = ns[e];
        tab.chunk[e] = chunks[e]; tab.lstride[e] = lstr[e];
        total += ns[e];
    }
    conv_small<<<(total + 255) / 256, 256, 0, stream>>>(tab, sp, flag, total);
    woutpad_kernel<<<256, 256, 0, stream>>>(woutI, boutI, sp + oWoutPad, sp + oBoutPad, flag);

    conv_T<<<dim3(16, 16, 6), 256, 0, stream>>>(wqI, wqkvT,          DD, DD, flag, 786432);
    conv_T<<<dim3(16, 16, 6), 256, 0, stream>>>(wkI, wqkvT + 262144, DD, DD, flag, 786432);
    conv_T<<<dim3(16, 16, 6), 256, 0, stream>>>(wvI, wqkvT + 524288, DD, DD, flag, 786432);
    conv_T<<<dim3(16, 16, 6), 256, 0, stream>>>(woI, woT, DD, DD, flag, 262144);
    conv_T<<<dim3(64, 16, 6), 256, 0, stream>>>(w1I, w1T, DD, DFF, flag, 1048576);
    conv_T<<<dim3(16, 64, 6), 256, 0, stream>>>(w2I, w2T, DFF, DD, flag, 1048576);

    embed_kernel<<<MTOT, 128, 0, stream>>>(x, sp + oTok, sp + oPos, h);

    for (int l = 0; l < NLAYERS; l++) {
        u16* wqkvTl = wqkvT + (size_t)l * 786432;
        u16* woTl   = woT + (size_t)l * 262144;
        u16* w1Tl   = w1T + (size_t)l * 1048576;
        u16* w2Tl   = w2T + (size_t)l * 1048576;

        ln_kernel<<<MTOT / 4, 256, 0, stream>>>(h, sp + oLn1s + l * DD, sp + oLn1b + l * DD, hn);

        gemm_bt<0><<<dim3(QS / 128, MTOT / 128), 256, 0, stream>>>(
            hn, wqkvTl, sp + oQkvB + l * QS, qkv, nullptr, MTOT, QS, DD, DD, flag);

        attn_kernel<<<MTOT / 4, 256, 0, stream>>>(qkv);

        gemm_bt<2><<<dim3(DD / 128, MTOT / 128), 256, 0, stream>>>(
            qkv, woTl, sp + oBo + l * DD, nullptr, h, MTOT, DD, DD, QS, flag);

        ln_kernel<<<MTOT / 4, 256, 0, stream>>>(h, sp + oLn2s + l * DD, sp + oLn2b + l * DD, hn);

        for (int half = 0; half < 2; half++) {
            const u16* Ahn = hn + (size_t)half * 16384 * DD;
            float* hHalf = h + (size_t)half * 16384 * DD;
            gemm_bt<1><<<dim3(DFF / 128, 16384 / 128), 256, 0, stream>>>(
                Ahn, w1Tl, sp + oB1 + l * DFF, mid, nullptr, 16384, DFF, DD, DD, flag);
            if (l < NLAYERS - 1) {
                gemm_bt<2><<<dim3(DD / 128, 16384 / 128), 256, 0, stream>>>(
                    mid, w2Tl, sp + oB2 + l * DD, nullptr, hHalf, 16384, DD, DFF, DFF, flag);
            } else {
                gemm_bt<4><<<dim3(DD / 128, 16384 / 128), 256, 0, stream>>>(
                    mid, w2Tl, sp + oB2 + l * DD, hn + (size_t)half * 16384 * DD, hHalf,
                    16384, DD, DFF, DFF, flag);
            }
        }
    }

    gemm_bt<3><<<dim3(1, MTOT / 128), 256, 0, stream>>>(
        hn, sp + oWoutPad, sp + oBoutPad, (u16*)d_out, (float*)d_out, MTOT, 128, DD, DD, flag);
}